// Round 6
// baseline (355.266 us; speedup 1.0000x reference)
//
#include <hip/hip_runtime.h>

namespace {

constexpr int H = 17, W = 17, NC = H * W;   // 289 cells
constexpr int SW = 20, SH = 19;             // LDS tile stride (elements), 1-wide zero halo
constexpr int NT = 320;                     // 5 waves; critical SIMD carries 2 (TLP)

#define PIN(x) asm volatile("" : "+v"(x))

__device__ __forceinline__ float clip10(float v) {
    return fminf(fmaxf(v, -10.f), 10.f);
}

__device__ __forceinline__ float max3f(float a, float b, float c) {
    return fmaxf(fmaxf(a, b), c);   // v_max3_f32
}

__device__ __forceinline__ float scent_at(int hy, int wx, const float* __restrict__ food) {
    const float SK[5][5] = {
        {0.f,   .125f, .25f, .125f, 0.f},
        {.125f, .25f,  .5f,  .25f,  .125f},
        {.25f,  .5f,   1.f,  .5f,   .25f},
        {.125f, .25f,  .5f,  .25f,  .125f},
        {0.f,   .125f, .25f, .125f, 0.f}};
    float sc = 0.f;
    #pragma unroll
    for (int dy = -2; dy <= 2; ++dy) {
        #pragma unroll
        for (int dx = -2; dx <= 2; ++dx) {
            const float k = SK[dy + 2][dx + 2];
            if (k != 0.f) {
                const int yy = hy + dy, xx = wx + dx;
                if (yy >= 0 && yy < H && xx >= 0 && xx < W)
                    sc = fmaf(k, food[yy * W + xx], sc);
            }
        }
    }
    return sc;
}

__launch_bounds__(NT, 2)
__global__ void ca_kernel(const float* __restrict__ cell_in,
                          const float* __restrict__ food,
                          const float* __restrict__ w3,
                          const float* __restrict__ b3,
                          const float* __restrict__ w4,
                          const float* __restrict__ b4,
                          const int* __restrict__ steps_p,
                          float* __restrict__ out)
{
    __shared__ float2 c01[SH * SW];    // channels 0,1 packed (b64 taps)
    __shared__ float  c2s[SH * SW];    // channel 2
    __shared__ float  scs[SH * SW];    // scent (pre-loop only)
    __shared__ float  xb[SH * SW];     // x[0] exchange for post-alive maxpool
    __shared__ float4 wlds[48];        // weights: per o, 3x float4 broadcast
    __shared__ float  red[NT];

    const int tid = (int)threadIdx.x;
    const int steps = steps_p[0];
    const bool act = tid < NC;

    // zero LDS (halo zeros are decision-equivalent to -inf pad: threshold 0.1 > 0)
    for (int i = tid; i < SH * SW; i += NT) {
        c01[i] = make_float2(0.f, 0.f);
        c2s[i] = 0.f; scs[i] = 0.f; xb[i] = 0.f;
    }
    // pack weights into LDS: wlds[3o]   = {w3[o,0], w3[o,1], w3[o,2], w3[o,4]/8}
    //                        wlds[3o+1] = {w3[o,5]/8, w3[o,6]/8, w3[o,8]/8, w3[o,9]/8}
    //                        wlds[3o+2] = {w3[o,10]/8, w4[0,o], w4[1,o], w4[2,o]}
    if (tid < 16) {
        const int o = tid;
        wlds[3*o]   = make_float4(w3[o*12+0], w3[o*12+1], w3[o*12+2], w3[o*12+4]*0.125f);
        wlds[3*o+1] = make_float4(w3[o*12+5]*0.125f, w3[o*12+6]*0.125f,
                                  w3[o*12+8]*0.125f, w3[o*12+9]*0.125f);
        wlds[3*o+2] = make_float4(w3[o*12+10]*0.125f, w4[o], w4[16+o], w4[32+o]);
    }
    __syncthreads();

    const int hy = act ? tid / W : 0;
    const int wx = act ? tid % W : 0;
    const int idx = (hy + 1) * SW + wx + 1;

    // per-cell state center values live in registers across the whole loop
    float cur0 = 0.f, cur1 = 0.f, cur2 = 0.f, sc = 0.f;
    if (act) {
        cur0 = cell_in[tid];
        cur1 = cell_in[NC + tid];
        cur2 = cell_in[2 * NC + tid];
        sc   = scent_at(hy, wx, food);
        c01[idx] = make_float2(cur0, cur1);
        c2s[idx] = cur2;
        scs[idx] = sc;
    }
    __syncthreads();

    // ---- fold loop-invariant scent perception into per-cell bias be[] ----
    float be[16];
    {
        const float s00 = scs[idx-SW-1], s01 = scs[idx-SW], s02 = scs[idx-SW+1];
        const float s10 = scs[idx-1],                       s12 = scs[idx+1];
        const float s20 = scs[idx+SW-1], s21 = scs[idx+SW], s22 = scs[idx+SW+1];
        const float dxs = ((s02-s00) + 2.f*(s12-s10) + (s22-s20)) * 0.125f;
        const float dys = ((s20+2.f*s21+s22) - (s00+2.f*s01+s02)) * 0.125f;
        #pragma unroll
        for (int o = 0; o < 16; ++o)
            be[o] = fmaf(w3[o*12+3], sc, fmaf(w3[o*12+7], dxs,
                    fmaf(w3[o*12+11], dys, b3[o])));
    }
    float b40 = b4[0], b41 = b4[1], b42 = b4[2];
    #pragma unroll
    for (int o = 0; o < 16; ++o) PIN(be[o]);
    PIN(b40); PIN(b41); PIN(b42);

    // ---- main loop: 2 barriers/step; weights broadcast-read from LDS ----
    for (int s = 0; s < steps; ++s) {
        float n0 = 0.f, n1 = 0.f, n2 = 0.f;
        bool pre = false;
        if (act) {
            // 8 neighbor taps per channel-pair (+ c2); centers from registers
            const float2 a00 = c01[idx-SW-1], a01 = c01[idx-SW], a02 = c01[idx-SW+1];
            const float2 a10 = c01[idx-1],                       a12 = c01[idx+1];
            const float2 a20 = c01[idx+SW-1], a21 = c01[idx+SW], a22 = c01[idx+SW+1];
            const float r00 = c2s[idx-SW-1], r01 = c2s[idx-SW], r02 = c2s[idx-SW+1];
            const float r10 = c2s[idx-1],                       r12 = c2s[idx+1];
            const float r20 = c2s[idx+SW-1], r21 = c2s[idx+SW], r22 = c2s[idx+SW+1];

            const float y0 = cur0, y1 = cur1, y2 = cur2;
            const float y3 = (a02.x-a00.x) + 2.f*(a12.x-a10.x) + (a22.x-a20.x);
            const float y4 = (a02.y-a00.y) + 2.f*(a12.y-a10.y) + (a22.y-a20.y);
            const float y5 = (r02-r00) + 2.f*(r12-r10) + (r22-r20);
            const float y6 = (a20.x+2.f*a21.x+a22.x) - (a00.x+2.f*a01.x+a02.x);
            const float y7 = (a20.y+2.f*a21.y+a22.y) - (a00.y+2.f*a01.y+a02.y);
            const float y8 = (r20+2.f*r21+r22) - (r00+2.f*r01+r02);
            pre = max3f(max3f(a00.x,a01.x,a02.x), max3f(a10.x,cur0,a12.x),
                        max3f(a20.x,a21.x,a22.x)) > 0.1f;

            float d0 = b40, d1 = b41, d2 = b42;
            #pragma unroll
            for (int o = 0; o < 16; ++o) {
                const float4 wa = wlds[3*o], wb = wlds[3*o+1], wc = wlds[3*o+2];
                float a = be[o];
                a = fmaf(wa.x, y0, a); a = fmaf(wa.y, y1, a);
                a = fmaf(wa.z, y2, a); a = fmaf(wa.w, y3, a);
                a = fmaf(wb.x, y4, a); a = fmaf(wb.y, y5, a);
                a = fmaf(wb.z, y6, a); a = fmaf(wb.w, y7, a);
                a = fmaf(wc.x, y8, a);
                a = fmaxf(a, 0.f);
                d0 = fmaf(wc.y, a, d0);
                d1 = fmaf(wc.z, a, d1);
                d2 = fmaf(wc.w, a, d2);
            }
            n0 = y0 + d0; n1 = y1 + d1; n2 = y2 + d2;
            xb[idx] = n0;
        }
        __syncthreads();
        if (act) {
            const float x00 = xb[idx-SW-1], x01 = xb[idx-SW], x02 = xb[idx-SW+1];
            const float x10 = xb[idx-1],                      x12 = xb[idx+1];
            const float x20 = xb[idx+SW-1], x21 = xb[idx+SW], x22 = xb[idx+SW+1];
            const float mx2 = max3f(max3f(x00,x01,x02), max3f(x10,n0,x12),
                                    max3f(x20,x21,x22));
            const float m = (pre && (mx2 > 0.1f)) ? 1.f : 0.f;
            cur0 = clip10(n0 * m);
            cur1 = clip10(n1 * m);
            cur2 = clip10(n2 * m);
            c01[idx] = make_float2(cur0, cur1);
            c2s[idx] = cur2;
        }
        __syncthreads();
    }

    // ---- outputs: cell (4*289) | food (289) | living_count (1) ----
    if (act) {
        out[tid]          = cur0;
        out[NC + tid]     = cur1;
        out[2 * NC + tid] = cur2;
        out[3 * NC + tid] = clip10(sc);
        out[4 * NC + tid] = food[tid];
        red[tid] = cur0;
    } else {
        red[tid] = 0.f;
    }
    __syncthreads();
    if (tid < 64) {
        float s2 = red[tid] + red[tid + 64] + red[tid + 128]
                 + red[tid + 192] + red[tid + 256];
        #pragma unroll
        for (int off = 32; off > 0; off >>= 1)
            s2 += __shfl_down(s2, off, 64);
        if (tid == 0) out[5 * NC] = s2;
    }
}

}  // namespace

extern "C" void kernel_launch(void* const* d_in, const int* in_sizes, int n_in,
                              void* d_out, int out_size, void* d_ws, size_t ws_size,
                              hipStream_t stream) {
    const float* cell = (const float*)d_in[0];
    const float* food = (const float*)d_in[1];
    const float* w3   = (const float*)d_in[2];
    const float* b3   = (const float*)d_in[3];
    const float* w4   = (const float*)d_in[4];
    const float* b4   = (const float*)d_in[5];
    const int*   st   = (const int*)d_in[6];
    float* out = (float*)d_out;
    ca_kernel<<<1, NT, 0, stream>>>(cell, food, w3, b3, w4, b4, st, out);
}